// Round 10
// baseline (218.478 us; speedup 1.0000x reference)
//
#include <hip/hip_runtime.h>

// ColorQuantizer: out[b,c,h,w] = palette[argmin_i dist(processed(x[b,:,h,w]), palette_i)][c]
// processed = relu(x@W1 + b1) @ W2 + b2   (all fp32, replicate reference op order)
//
// R10: block-residency experiment. Across R1-R9, resident waves/CU tracked
// BLOCKS/CU (~4-6) regardless of VGPR headroom (R8: 4 blocks = 16 waves at
// VGPR=40 though 48 allowed). Same 8192-tile work decomposition as R8 (best,
// 89.6us) but BLOCK=1024 (16 waves/block, grid 2048): if residency is
// block-granular, resident waves quadruple -> input-latency (L3 ~500cy /
// HBM ~900cy) finally covered. Per-pixel math BIT-IDENTICAL to verified
// R5/R8 (absmax=0): SGPR weights, psq-seeded distance chain, int-key argmin
// with med3 second-min, widened screen + exact sqrt replay fallback.

typedef float f4 __attribute__((ext_vector_type(4)));

static __device__ __forceinline__ int imin32(int a, int b){ return a < b ? a : b; }
static __device__ __forceinline__ int med3_i32(int a, int b, int c){
    int d; asm("v_med3_i32 %0, %1, %2, %3" : "=v"(d) : "v"(a), "v"(b), "v"(c)); return d; }

constexpr int COLI[16][3] = {
  {0,0,0},{255,255,255},{255,0,0},{0,255,0},{0,0,255},{255,255,0},
  {255,0,255},{0,255,255},{128,128,128},{128,0,0},{0,128,0},{0,0,128},
  {128,128,0},{128,0,128},{0,128,128},{192,192,192}
};
constexpr float PVF(int v){ return (float)v/255.0f*2.0f-1.0f; }
constexpr float PXc(int i){ return PVF(COLI[i][0]); }
constexpr float PYc(int i){ return PVF(COLI[i][1]); }
constexpr float PZc(int i){ return PVF(COLI[i][2]); }
// sum(PALETTE*PALETTE, axis=-1) with the reference's reduce order: (x*x + y*y) + z*z
constexpr float PSQc(int i){ return (PXc(i)*PXc(i) + PYc(i)*PYc(i)) + PZc(i)*PZc(i); }

// {px, py, pz, psq} per palette entry (gather staging + exact fallback).
#define PE(i) {PXc(i), PYc(i), PZc(i), PSQc(i)}
__device__ const float PAL4f[16][4] = {
  PE(0),PE(1),PE(2),PE(3),PE(4),PE(5),PE(6),PE(7),
  PE(8),PE(9),PE(10),PE(11),PE(12),PE(13),PE(14),PE(15)
};

constexpr int HW    = 512*512;   // per-channel plane
constexpr int PXT   = 4;         // pixels per thread (one float4 per plane)
constexpr int BLOCK = 1024;      // 16 waves per block

// Rare path: bit-exact replay of the reference distance loop (correctly-rounded
// sqrtf, first-occurrence argmin over d). Inputs p0..p2, psq are bit-exact
// reference values, so this reproduces the reference winner exactly.
__device__ __attribute__((noinline)) int argmin_exact(float p0, float p1, float p2, float psq)
{
#pragma clang fp contract(off)
    float bd = 3.4e38f;
    int   bi = 0;
#pragma unroll 1
    for (int i = 0; i < 16; ++i) {
        const float px = PAL4f[i][0], py = PAL4f[i][1], pz = PAL4f[i][2], pq = PAL4f[i][3];
        float dot = __builtin_fmaf(p2, pz, __builtin_fmaf(p1, py, p0*px));
        float sq  = (psq - 2.0f*dot) + pq;
        float d   = sqrtf(fmaxf(sq, 0.0f));
        if (d < bd) { bd = d; bi = i; }
    }
    return bi;
}

__global__ __launch_bounds__(BLOCK) void cq_kernel(
    const float* __restrict__ x,  const float* __restrict__ W1g,
    const float* __restrict__ b1g, const float* __restrict__ W2g,
    const float* __restrict__ b2g, float* __restrict__ out)
{
#pragma clang fp contract(off)
    __shared__ f4 sPAL[16];      // final gather table only

    const int t = threadIdx.x;

    // 64 blocks per image, 4096 px per block.
    const int img = blockIdx.x >> 6;
    const int hwb = (blockIdx.x & 63) << 12;
    const size_t base = (size_t)img * (size_t)(3*HW) + (size_t)hwb;
    const int oa = 4*t;           // pixels [4t, 4t+4)

    // 3 unit-stride input loads (16KB contiguous per block per plane).
    f4 a0 = *(const f4*)(x + base + oa);
    f4 c0 = *(const f4*)(x + base + HW + oa);
    f4 e0 = *(const f4*)(x + base + 2*HW + oa);

    if (t < 16) sPAL[t] = *(const f4*)&PAL4f[t][0];
    __syncthreads();

    float X0[PXT], X1[PXT], X2[PXT];
    X0[0]=a0.x; X0[1]=a0.y; X0[2]=a0.z; X0[3]=a0.w;
    X1[0]=c0.x; X1[1]=c0.y; X1[2]=c0.z; X1[3]=c0.w;
    X2[0]=e0.x; X2[1]=e0.y; X2[2]=e0.z; X2[3]=e0.w;

    // processed accumulators; dot runs from 0 so fma(h,u,0) == h*u exactly
    float P0[PXT], P1[PXT], P2[PXT];
#pragma unroll
    for (int k = 0; k < PXT; ++k) { P0[k]=0.0f; P1[k]=0.0f; P2[k]=0.0f; }

    // Fused MLP: weights via uniform loads -> SGPRs; each VALU op reads the
    // scalar operand directly (<=1 SGPR per instruction). 8 j's per group so
    // s_loads batch and hide under the previous group.
#pragma unroll 1
    for (int jg = 0; jg < 32; jg += 8) {
#pragma unroll
        for (int jj = 0; jj < 8; ++jj) {
            const int j = jg + jj;
            const float w0 = W1g[j], w1 = W1g[32+j], w2 = W1g[64+j], bb = b1g[j];
            const float u0 = W2g[3*j], u1 = W2g[3*j+1], u2 = W2g[3*j+2];
#pragma unroll
            for (int k = 0; k < PXT; ++k) {
                float h = __builtin_fmaf(X2[k], w2, __builtin_fmaf(X1[k], w1, X0[k]*w0));
                h = h + bb;
                h = fmaxf(h, 0.0f);
                P0[k] = __builtin_fmaf(h, u0, P0[k]);
                P1[k] = __builtin_fmaf(h, u1, P1[k]);
                P2[k] = __builtin_fmaf(h, u2, P2[k]);
            }
        }
    }

    // Bias + psq in exact reference order: (p0*p0 + p1*p1) + p2*p2
    const float bc0 = b2g[0], bc1 = b2g[1], bc2 = b2g[2];
    float p0a[PXT], p1a[PXT], p2a[PXT], psqa[PXT];
#pragma unroll
    for (int k = 0; k < PXT; ++k) {
        const float p0 = P0[k] + bc0;
        const float p1 = P1[k] + bc1;
        const float p2 = P2[k] + bc2;
        p0a[k] = p0; p1a[k] = p1; p2a[k] = p2;
        psqa[k] = (p0*p0 + p1*p1) + p2*p2;   // muls+adds only (contract off)
    }

    // Distance phase, fully unrolled so palette coefficients fold to
    // immediates. sq' = fma(p0,-2px, fma(p1,-2py, fma(p2,-2pz, psq))) + pq
    // -- psq-seeded chain; |sq' - sq_ref| <= ~4 ulp of (psq+4), covered by
    // the widened screen. Keys: signed-int order == float order for sq' >= 0;
    // index rides in the low 4 bits (first-occurrence ties).
    int m1k[PXT], m2k[PXT];
#pragma unroll
    for (int p = 0; p < PXT; ++p) { m1k[p] = 0x7FFFFFFF; m2k[p] = 0x7FFFFFFF; }

#pragma unroll
    for (int i = 0; i < 16; ++i) {
        const float mx = -2.0f*PXc(i);   // exact (pow2 scale), compile-time
        const float my = -2.0f*PYc(i);
        const float mz = -2.0f*PZc(i);
        const float pq = PSQc(i);
#pragma unroll
        for (int k = 0; k < PXT; ++k) {
            float tq = __builtin_fmaf(p2a[k], mz, psqa[k]);
            tq = __builtin_fmaf(p1a[k], my, tq);
            tq = __builtin_fmaf(p0a[k], mx, tq);
            tq = tq + pq;                                  // ~= reference sq
            const int kk = (__float_as_int(tq) & (int)0xFFFFFFF0) | i;
            // m2 = min(m2, max(kk, m1)) == med3(kk, m1, m2)  [m1 <= m2 inv.]
            m2k[k] = med3_i32(kk, m1k[k], m2k[k]);
            m1k[k] = imin32(m1k[k], kk);
        }
    }

    // Screen: fallback if min <= 0 (negative-dip / degenerate zone) or the
    // absolute gap is within 1e-4*(psq+4) (covers: 4-ulp association error of
    // the psq-seeded chain, 16-ulp key truncation, sqrt rounding collisions —
    // all bounded by ~1e-6*(psq+4)). Fallback replays the reference exactly.
    int bi[PXT];
#pragma unroll
    for (int p = 0; p < PXT; ++p) {
        bi[p] = m1k[p] & 15;
        const float m1f = __int_as_float(m1k[p] & (int)0xFFFFFFF0);
        const float m2f = __int_as_float(m2k[p] & (int)0xFFFFFFF0);
        const float thr = 1e-4f * (psqa[p] + 4.0f);
        if (__builtin_expect(m1f <= 0.0f || (m2f - m1f) <= thr, 0)) {
            bi[p] = argmin_exact(p0a[p], p1a[p], p2a[p], psqa[p]);
        }
    }

    // Palette gather from LDS + transpose to channel-planar unit-stride stores.
    f4 col[PXT];
#pragma unroll
    for (int p = 0; p < PXT; ++p) col[p] = sPAL[bi[p]];

    float* op = out + base;
    f4 o;
    o.x=col[0].x; o.y=col[1].x; o.z=col[2].x; o.w=col[3].x;
    __builtin_nontemporal_store(o, (f4*)(op + oa));
    o.x=col[0].y; o.y=col[1].y; o.z=col[2].y; o.w=col[3].y;
    __builtin_nontemporal_store(o, (f4*)(op + HW + oa));
    o.x=col[0].z; o.y=col[1].z; o.z=col[2].z; o.w=col[3].z;
    __builtin_nontemporal_store(o, (f4*)(op + 2*HW + oa));
}

extern "C" void kernel_launch(void* const* d_in, const int* in_sizes, int n_in,
                              void* d_out, int out_size, void* d_ws, size_t ws_size,
                              hipStream_t stream) {
    const float* x  = (const float*)d_in[0];
    const float* W1 = (const float*)d_in[1];
    const float* b1 = (const float*)d_in[2];
    const float* W2 = (const float*)d_in[3];
    const float* b2 = (const float*)d_in[4];
    float* outp = (float*)d_out;

    constexpr int NPIX = 32 * HW;                    // 8,388,608
    constexpr int GRID = NPIX / (BLOCK * PXT);       // 2048 blocks, exact
    hipLaunchKernelGGL(cq_kernel, dim3(GRID), dim3(BLOCK), 0, stream,
                       x, W1, b1, W2, b2, outp);
}

// Round 11
// 209.408 us; speedup vs baseline: 1.0433x; 1.0433x over previous
//
#include <hip/hip_runtime.h>

// ColorQuantizer: out[b,c,h,w] = palette[argmin_i dist(processed(x[b,:,h,w]), palette_i)][c]
// processed = relu(x@W1 + b1) @ W2 + b2   (all fp32, replicate reference op order)
//
// R11: block-granularity experiment (the only empirically-positive axis).
// Cross-round ladder: 2048blk=97-108us, 4096blk=100us, 8192blk=89.6us (R8
// best). R10 (2048x16waves) vs R8 (8192x4) held total waves fixed and small
// blocks won 9% -> CU fill looks block-dispatch-granular. R11 = R8 with
// BLOCK 256->128 (grid 16384, waves unchanged 32768, per-wave work
// unchanged). Per-pixel math BIT-IDENTICAL to verified R5/R8 (absmax=0):
// SGPR weights, psq-seeded distance chain, int-key argmin with med3
// second-min, widened screen + exact sqrt replay fallback.

typedef float f4 __attribute__((ext_vector_type(4)));

static __device__ __forceinline__ int imin32(int a, int b){ return a < b ? a : b; }
static __device__ __forceinline__ int med3_i32(int a, int b, int c){
    int d; asm("v_med3_i32 %0, %1, %2, %3" : "=v"(d) : "v"(a), "v"(b), "v"(c)); return d; }

constexpr int COLI[16][3] = {
  {0,0,0},{255,255,255},{255,0,0},{0,255,0},{0,0,255},{255,255,0},
  {255,0,255},{0,255,255},{128,128,128},{128,0,0},{0,128,0},{0,0,128},
  {128,128,0},{128,0,128},{0,128,128},{192,192,192}
};
constexpr float PVF(int v){ return (float)v/255.0f*2.0f-1.0f; }
constexpr float PXc(int i){ return PVF(COLI[i][0]); }
constexpr float PYc(int i){ return PVF(COLI[i][1]); }
constexpr float PZc(int i){ return PVF(COLI[i][2]); }
// sum(PALETTE*PALETTE, axis=-1) with the reference's reduce order: (x*x + y*y) + z*z
constexpr float PSQc(int i){ return (PXc(i)*PXc(i) + PYc(i)*PYc(i)) + PZc(i)*PZc(i); }

// {px, py, pz, psq} per palette entry (gather staging + exact fallback).
#define PE(i) {PXc(i), PYc(i), PZc(i), PSQc(i)}
__device__ const float PAL4f[16][4] = {
  PE(0),PE(1),PE(2),PE(3),PE(4),PE(5),PE(6),PE(7),
  PE(8),PE(9),PE(10),PE(11),PE(12),PE(13),PE(14),PE(15)
};

constexpr int HW    = 512*512;   // per-channel plane
constexpr int PXT   = 4;         // pixels per thread (one float4 per plane)
constexpr int BLOCK = 128;       // 2 waves per block (R11: finer dispatch grain)

// Rare path: bit-exact replay of the reference distance loop (correctly-rounded
// sqrtf, first-occurrence argmin over d). Inputs p0..p2, psq are bit-exact
// reference values, so this reproduces the reference winner exactly.
__device__ __attribute__((noinline)) int argmin_exact(float p0, float p1, float p2, float psq)
{
#pragma clang fp contract(off)
    float bd = 3.4e38f;
    int   bi = 0;
#pragma unroll 1
    for (int i = 0; i < 16; ++i) {
        const float px = PAL4f[i][0], py = PAL4f[i][1], pz = PAL4f[i][2], pq = PAL4f[i][3];
        float dot = __builtin_fmaf(p2, pz, __builtin_fmaf(p1, py, p0*px));
        float sq  = (psq - 2.0f*dot) + pq;
        float d   = sqrtf(fmaxf(sq, 0.0f));
        if (d < bd) { bd = d; bi = i; }
    }
    return bi;
}

__global__ __launch_bounds__(BLOCK) void cq_kernel(
    const float* __restrict__ x,  const float* __restrict__ W1g,
    const float* __restrict__ b1g, const float* __restrict__ W2g,
    const float* __restrict__ b2g, float* __restrict__ out)
{
#pragma clang fp contract(off)
    __shared__ f4 sPAL[16];      // final gather table only

    const int t = threadIdx.x;

    // 512 blocks per image, 512 px per block.
    const int img = blockIdx.x >> 9;
    const int hwb = (blockIdx.x & 511) << 9;
    const size_t base = (size_t)img * (size_t)(3*HW) + (size_t)hwb;
    const int oa = 4*t;           // pixels [4t, 4t+4)

    // 3 unit-stride input loads (2KB contiguous per block per plane).
    f4 a0 = *(const f4*)(x + base + oa);
    f4 c0 = *(const f4*)(x + base + HW + oa);
    f4 e0 = *(const f4*)(x + base + 2*HW + oa);

    if (t < 16) sPAL[t] = *(const f4*)&PAL4f[t][0];
    __syncthreads();

    float X0[PXT], X1[PXT], X2[PXT];
    X0[0]=a0.x; X0[1]=a0.y; X0[2]=a0.z; X0[3]=a0.w;
    X1[0]=c0.x; X1[1]=c0.y; X1[2]=c0.z; X1[3]=c0.w;
    X2[0]=e0.x; X2[1]=e0.y; X2[2]=e0.z; X2[3]=e0.w;

    // processed accumulators; dot runs from 0 so fma(h,u,0) == h*u exactly
    float P0[PXT], P1[PXT], P2[PXT];
#pragma unroll
    for (int k = 0; k < PXT; ++k) { P0[k]=0.0f; P1[k]=0.0f; P2[k]=0.0f; }

    // Fused MLP: weights via uniform loads -> SGPRs; each VALU op reads the
    // scalar operand directly (<=1 SGPR per instruction). 8 j's per group so
    // s_loads batch and hide under the previous group.
#pragma unroll 1
    for (int jg = 0; jg < 32; jg += 8) {
#pragma unroll
        for (int jj = 0; jj < 8; ++jj) {
            const int j = jg + jj;
            const float w0 = W1g[j], w1 = W1g[32+j], w2 = W1g[64+j], bb = b1g[j];
            const float u0 = W2g[3*j], u1 = W2g[3*j+1], u2 = W2g[3*j+2];
#pragma unroll
            for (int k = 0; k < PXT; ++k) {
                float h = __builtin_fmaf(X2[k], w2, __builtin_fmaf(X1[k], w1, X0[k]*w0));
                h = h + bb;
                h = fmaxf(h, 0.0f);
                P0[k] = __builtin_fmaf(h, u0, P0[k]);
                P1[k] = __builtin_fmaf(h, u1, P1[k]);
                P2[k] = __builtin_fmaf(h, u2, P2[k]);
            }
        }
    }

    // Bias + psq in exact reference order: (p0*p0 + p1*p1) + p2*p2
    const float bc0 = b2g[0], bc1 = b2g[1], bc2 = b2g[2];
    float p0a[PXT], p1a[PXT], p2a[PXT], psqa[PXT];
#pragma unroll
    for (int k = 0; k < PXT; ++k) {
        const float p0 = P0[k] + bc0;
        const float p1 = P1[k] + bc1;
        const float p2 = P2[k] + bc2;
        p0a[k] = p0; p1a[k] = p1; p2a[k] = p2;
        psqa[k] = (p0*p0 + p1*p1) + p2*p2;   // muls+adds only (contract off)
    }

    // Distance phase, fully unrolled so palette coefficients fold to
    // immediates. sq' = fma(p0,-2px, fma(p1,-2py, fma(p2,-2pz, psq))) + pq
    // -- psq-seeded chain; |sq' - sq_ref| <= ~4 ulp of (psq+4), covered by
    // the widened screen. Keys: signed-int order == float order for sq' >= 0;
    // index rides in the low 4 bits (first-occurrence ties).
    int m1k[PXT], m2k[PXT];
#pragma unroll
    for (int p = 0; p < PXT; ++p) { m1k[p] = 0x7FFFFFFF; m2k[p] = 0x7FFFFFFF; }

#pragma unroll
    for (int i = 0; i < 16; ++i) {
        const float mx = -2.0f*PXc(i);   // exact (pow2 scale), compile-time
        const float my = -2.0f*PYc(i);
        const float mz = -2.0f*PZc(i);
        const float pq = PSQc(i);
#pragma unroll
        for (int k = 0; k < PXT; ++k) {
            float tq = __builtin_fmaf(p2a[k], mz, psqa[k]);
            tq = __builtin_fmaf(p1a[k], my, tq);
            tq = __builtin_fmaf(p0a[k], mx, tq);
            tq = tq + pq;                                  // ~= reference sq
            const int kk = (__float_as_int(tq) & (int)0xFFFFFFF0) | i;
            // m2 = min(m2, max(kk, m1)) == med3(kk, m1, m2)  [m1 <= m2 inv.]
            m2k[k] = med3_i32(kk, m1k[k], m2k[k]);
            m1k[k] = imin32(m1k[k], kk);
        }
    }

    // Screen: fallback if min <= 0 (negative-dip / degenerate zone) or the
    // absolute gap is within 1e-4*(psq+4) (covers: 4-ulp association error of
    // the psq-seeded chain, 16-ulp key truncation, sqrt rounding collisions —
    // all bounded by ~1e-6*(psq+4)). Fallback replays the reference exactly.
    int bi[PXT];
#pragma unroll
    for (int p = 0; p < PXT; ++p) {
        bi[p] = m1k[p] & 15;
        const float m1f = __int_as_float(m1k[p] & (int)0xFFFFFFF0);
        const float m2f = __int_as_float(m2k[p] & (int)0xFFFFFFF0);
        const float thr = 1e-4f * (psqa[p] + 4.0f);
        if (__builtin_expect(m1f <= 0.0f || (m2f - m1f) <= thr, 0)) {
            bi[p] = argmin_exact(p0a[p], p1a[p], p2a[p], psqa[p]);
        }
    }

    // Palette gather from LDS + transpose to channel-planar unit-stride stores.
    f4 col[PXT];
#pragma unroll
    for (int p = 0; p < PXT; ++p) col[p] = sPAL[bi[p]];

    float* op = out + base;
    f4 o;
    o.x=col[0].x; o.y=col[1].x; o.z=col[2].x; o.w=col[3].x;
    __builtin_nontemporal_store(o, (f4*)(op + oa));
    o.x=col[0].y; o.y=col[1].y; o.z=col[2].y; o.w=col[3].y;
    __builtin_nontemporal_store(o, (f4*)(op + HW + oa));
    o.x=col[0].z; o.y=col[1].z; o.z=col[2].z; o.w=col[3].z;
    __builtin_nontemporal_store(o, (f4*)(op + 2*HW + oa));
}

extern "C" void kernel_launch(void* const* d_in, const int* in_sizes, int n_in,
                              void* d_out, int out_size, void* d_ws, size_t ws_size,
                              hipStream_t stream) {
    const float* x  = (const float*)d_in[0];
    const float* W1 = (const float*)d_in[1];
    const float* b1 = (const float*)d_in[2];
    const float* W2 = (const float*)d_in[3];
    const float* b2 = (const float*)d_in[4];
    float* outp = (float*)d_out;

    constexpr int NPIX = 32 * HW;                    // 8,388,608
    constexpr int GRID = NPIX / (BLOCK * PXT);       // 16384 blocks, exact
    hipLaunchKernelGGL(cq_kernel, dim3(GRID), dim3(BLOCK), 0, stream,
                       x, W1, b1, W2, b2, outp);
}